// Round 24
// baseline (156.372 us; speedup 1.0000x reference)
//
#include <hip/hip_runtime.h>
#include <hip/hip_bf16.h>
#include <math.h>

#define SEQ   2048
#define NB    4
#define CDIM  512
#define NHEAD 8
#define HD    64
// scale * log2(e): folded into K channels at the qkv GEMM epilogue
#define SL    (0.125f * 1.4426950408889634f)

typedef __attribute__((ext_vector_type(8))) short short8;
typedef __attribute__((ext_vector_type(8))) _Float16 f16x8;
typedef __attribute__((ext_vector_type(4))) float f32x4;
typedef __attribute__((ext_vector_type(16))) float f32x16;

__device__ inline f32x16 mfma32(f16x8 a, f16x8 b, f32x16 c) {
    return __builtin_amdgcn_mfma_f32_32x32x16_f16(a, b, c, 0, 0, 0);
}
__device__ inline f32x4 mfmaB(short8 a, short8 b, f32x4 c) {
    return __builtin_amdgcn_mfma_f32_16x16x32_bf16(a, b, c, 0, 0, 0);
}

__device__ inline ushort bf16_rne(float f) {
    union { float f; unsigned u; } c; c.f = f;
    unsigned u = c.u + 0x7fffu + ((c.u >> 16) & 1u);
    return (ushort)(u >> 16);
}
__device__ inline float bf16_to_f(ushort h) {
    union { unsigned u; float f; } c; c.u = ((unsigned)h) << 16;
    return c.f;
}
// pack two f32 -> one VGPR of 2x f16 (RTZ)
__device__ inline unsigned pk2u(float a, float b) {
    auto p = __builtin_amdgcn_cvt_pkrtz(a, b);
    union { decltype(p) v; unsigned u; } c; c.v = p; return c.u;
}
// raw hardware 2^x via compiler builtin (hazards handled by compiler)
__device__ inline float fexp2(float x) { return __builtin_amdgcn_exp2f(x); }

// LDS tile layout (GEMM staging): [rows][64 cols of 2B] = 128B pitch, swizzled.
__device__ inline int swz_off(int row, int byte_in_row) {
    return row * 128 + (byte_in_row ^ ((((row & 7) ^ ((row >> 3) & 7))) << 4));
}
__device__ inline short8 fragB(const ushort* base, int row, int kbyte) {
    return *(const short8*)(base + (swz_off(row, kbyte) >> 1));
}

// stage 128x64 2B tile (16KB) via global_load_lds (width 16): LINEAR LDS dest,
// per-lane INVERSE-SWIZZLED global source (XOR swizzle is an involution, so
// LDS content is identical to the old reg-staged swizzled layout).
// src row pitch = 512 elems. 16 x 1KB wave-chunks; wave w owns chunks 4w..4w+3.
__device__ inline void stage128_lds(ushort* dst, const ushort* src, int tid) {
    const int w = tid >> 6, lane = tid & 63;
    #pragma unroll
    for (int i = 0; i < 4; ++i) {
        const int chunk = w * 4 + i;                 // 1KB LDS chunk index
        const int o = chunk * 1024 + lane * 16;      // this lane's dest byte
        const int row = o >> 7;
        const int byte = (o & 127) ^ ((((row & 7) ^ ((row >> 3) & 7))) << 4);
        const ushort* s = src + (size_t)row * 512 + (byte >> 1);
        __builtin_amdgcn_global_load_lds(
            (const __attribute__((address_space(1))) unsigned int*)s,
            (__attribute__((address_space(3))) unsigned int*)(dst + chunk * 512),
            16, 0, 0);
    }
}

// Fragment-major blob geometry (per bh, 2B elems):
//  Q_blk/K_blk: [chunk(64)][ks(4)][lane(64)][e(8)]  (chunk stride 2048)
//  V_blk: [ic(64)][ksp(2)][dh(2)][lane(64)][e(8)]

// ---------------------------------------------------------------------------
// conv_w: w_qkv -> bf16 hi only (qkv GEMM is 1-term); w_proj -> hi/lo split.
// ---------------------------------------------------------------------------
__global__ __launch_bounds__(256)
void conv_w(const float* __restrict__ w1, const float* __restrict__ w2,
            ushort* __restrict__ w1h, ushort* __restrict__ w1l,
            ushort* __restrict__ w2h, ushort* __restrict__ w2l)
{
    const size_t NW1 = (size_t)3 * CDIM * CDIM;
    size_t i = ((size_t)blockIdx.x * 256 + threadIdx.x) * 8;
    const bool isW1 = (i < NW1);
    const float* src; ushort *dh, *dl;
    if (isW1) { src = w1 + i; dh = w1h + i; dl = w1l + i; }
    else { size_t j = i - NW1; src = w2 + j; dh = w2h + j; dl = w2l + j; }
    float4 a = *(const float4*)src, b = *(const float4*)(src + 4);
    float f[8] = {a.x, a.y, a.z, a.w, b.x, b.y, b.z, b.w};
    short8 hv, lv;
    #pragma unroll
    for (int e = 0; e < 8; ++e) {
        ushort hi = bf16_rne(f[e]);
        hv[e] = (short)hi;
        lv[e] = (short)bf16_rne(f[e] - bf16_to_f(hi));
    }
    *(short8*)dh = hv;
    if (!isW1) *(short8*)dl = lv;   // lo half only needed for w_proj
}

// ---------------------------------------------------------------------------
// conv_x: x[b][c][n] f32 -> xT[b][n][c] plain bf16 (LDS-tiled transpose)
// ---------------------------------------------------------------------------
__global__ __launch_bounds__(256)
void conv_x(const float* __restrict__ x, ushort* __restrict__ xh)
{
    __shared__ float T[64][65];
    const int n0 = blockIdx.x * 64, c0 = blockIdx.y * 64, b = blockIdx.z;
    const int t = threadIdx.x, r = t >> 2, q = t & 3;
    const float* src = x + ((size_t)b * CDIM + c0 + r) * SEQ + n0 + q * 16;
    #pragma unroll
    for (int c = 0; c < 4; ++c) {
        float4 v = *(const float4*)(src + c * 4);
        T[r][q * 16 + c * 4 + 0] = v.x; T[r][q * 16 + c * 4 + 1] = v.y;
        T[r][q * 16 + c * 4 + 2] = v.z; T[r][q * 16 + c * 4 + 3] = v.w;
    }
    __syncthreads();
    short8 hv[2];
    #pragma unroll
    for (int k = 0; k < 16; ++k)
        hv[k >> 3][k & 7] = (short)bf16_rne(T[q * 16 + k][r]);
    size_t o = ((size_t)b * SEQ + n0 + r) * CDIM + c0 + q * 16;
    *(short8*)(xh + o) = hv[0]; *(short8*)(xh + o + 8) = hv[1];
}

// ---------------------------------------------------------------------------
// Split-bf16 MFMA GEMM: D[m][n] = sum_k A[m][k]*B[n][k], K=512.
// Block 128m x 128n, BK=64, 4 waves (2x2), 64x64 per wave.
// Staging via global_load_lds (linear dest + pre-swizzled source).
// MODE 0 (qkv): A = xT plain bf16, B = wh plain bf16 (1 MFMA term); m=seq,
//    n=ch -> q/k into fragment-major Q_blk/K_blk fp16 (K scaled SL), v -> vT.
// MODE 1 (proj): A = w split, B = aot split (3 terms); m=co, n=seq -> out+bias
// ---------------------------------------------------------------------------
template<int MODE>
__global__ __launch_bounds__(256)
void gemm_sp(const ushort* __restrict__ A0, const ushort* __restrict__ A1, size_t sA,
             const ushort* __restrict__ B0, const ushort* __restrict__ B1, size_t sB,
             _Float16* __restrict__ qblk, _Float16* __restrict__ kblk,
             _Float16* __restrict__ vT,
             float* __restrict__ outp, const float* __restrict__ bias)
{
    const int bn = blockIdx.x * 128, bm = blockIdx.y * 128, bat = blockIdx.z;
    __shared__ __align__(16) ushort sA0[8192], sA1[8192], sB0[8192], sB1[8192];
    const int tid = threadIdx.x;
    const int w = tid >> 6, lane = tid & 63, l15 = lane & 15, g = lane >> 4;
    const int wm = w >> 1, wn = w & 1;
    const ushort* Ah = A0 + sA * bat + (size_t)bm * 512;
    const ushort* Al = (MODE == 1) ? A1 + sA * bat + (size_t)bm * 512 : nullptr;
    const ushort* Bh = B0 + sB * bat + (size_t)bn * 512;
    const ushort* Bl = (MODE == 1) ? B1 + sB * bat + (size_t)bn * 512 : nullptr;

    f32x4 acc[4][4] = {};

    for (int k0 = 0; k0 < 512; k0 += 64) {
        __syncthreads();
        stage128_lds(sA0, Ah + k0, tid);
        stage128_lds(sB0, Bh + k0, tid);
        if (MODE == 1) {
            stage128_lds(sA1, Al + k0, tid);
            stage128_lds(sB1, Bl + k0, tid);
        }
        __syncthreads();
        #pragma unroll
        for (int kh = 0; kh < 2; ++kh) {
            short8 bh[4], bl[4];
            #pragma unroll
            for (int nf = 0; nf < 4; ++nf) {
                bh[nf] = fragB(sB0, 64 * wn + 16 * nf + l15, kh * 64 + g * 16);
                if (MODE == 1)
                    bl[nf] = fragB(sB1, 64 * wn + 16 * nf + l15, kh * 64 + g * 16);
            }
            #pragma unroll
            for (int mf = 0; mf < 4; ++mf) {
                short8 ah = fragB(sA0, 64 * wm + 16 * mf + l15, kh * 64 + g * 16);
                #pragma unroll
                for (int nf = 0; nf < 4; ++nf) {
                    acc[mf][nf] = mfmaB(ah, bh[nf], acc[mf][nf]);
                    if (MODE == 1)
                        acc[mf][nf] = mfmaB(ah, bl[nf], acc[mf][nf]);
                }
                if (MODE == 1) {
                    short8 al = fragB(sA1, 64 * wm + 16 * mf + l15, kh * 64 + g * 16);
                    #pragma unroll
                    for (int nf = 0; nf < 4; ++nf)
                        acc[mf][nf] = mfmaB(al, bh[nf], acc[mf][nf]);
                }
            }
        }
    }

    if (MODE == 0) {
        #pragma unroll
        for (int nf = 0; nf < 4; ++nf) {
            const int c0 = bn + 64 * wn + 16 * nf;   // frag-uniform (16 | boundaries)
            const int h = c0 / 192, rr = c0 % 192;
            if (rr < 128) {
                // q (rr<64) or k (64..127): fragment-major blob, K scaled by SL
                const float sc = (rr < 64) ? 1.0f : SL;
                const int dpr = (rr & 63) + l15;            // d' in [0,64)
                _Float16* blob = (rr < 64) ? qblk : kblk;
                _Float16* base = blob + (size_t)(bat * NHEAD + h) * (SEQ * 64)
                               + (dpr >> 4) * 512 + (((dpr >> 3) & 1) * 32) * 8
                               + (dpr & 7);
                #pragma unroll
                for (int mf = 0; mf < 4; ++mf)
                    #pragma unroll
                    for (int r = 0; r < 4; ++r) {
                        const int sj = bm + 64 * wm + 16 * mf + 4 * g + r;
                        base[(sj >> 5) * 2048 + (sj & 31) * 8] =
                            (_Float16)(acc[mf][nf][r] * sc);
                    }
            } else {
                _Float16* base = vT + ((size_t)(bat * NHEAD + h) * SEQ) * HD + (rr - 128) + l15;
                #pragma unroll
                for (int mf = 0; mf < 4; ++mf)
                    #pragma unroll
                    for (int r = 0; r < 4; ++r) {
                        const int sj = bm + 64 * wm + 16 * mf + 4 * g + r;
                        base[(size_t)sj * HD] = (_Float16)acc[mf][nf][r];
                    }
            }
        }
    } else {
        #pragma unroll
        for (int mf = 0; mf < 4; ++mf)
            #pragma unroll
            for (int r = 0; r < 4; ++r) {
                const int co = bm + 64 * wm + 16 * mf + 4 * g + r;
                const float bv = bias[co];
                float* base = outp + ((size_t)bat * CDIM + co) * SEQ + bn + 64 * wn + l15;
                #pragma unroll
                for (int nf = 0; nf < 4; ++nf)
                    base[16 * nf] = acc[mf][nf][r] + bv;
            }
    }
}

// ---------------------------------------------------------------------------
// Pass 1 v9 (128-i blocks, fused V prescale): cvals_i = -0.5*log2 sum_j 2^S,
// then scale/transpose this block's 128 V rows into V_blk using the fresh c.
// XCD-aware bh decode. K-frags (4 chunks) hoisted; j-reduction lane-local.
// ---------------------------------------------------------------------------
__global__ __launch_bounds__(256, 3)
void attn_pass1(const _Float16* __restrict__ qblk, const _Float16* __restrict__ kblk,
                const _Float16* __restrict__ vT, float* __restrict__ cvals,
                _Float16* __restrict__ vblk)
{
    const int lb = blockIdx.x;         // 512 blocks
    const int xcd = lb & 7, idx = lb >> 3;
    const int bh = xcd * 4 + (idx & 3);
    const int ib = idx >> 2;           // 0..15 (128-i tile)
    const _Float16* qb = qblk + (size_t)bh * (SEQ * 64);
    const _Float16* kb = kblk + (size_t)bh * (SEQ * 64);
    const int tid = threadIdx.x, w = tid >> 6, lane = tid & 63;

    __shared__ float red[4][4][32];
    __shared__ float cshare[128];
    __shared__ float T[64][65];

    // hoist K B-frags for the block's four i-chunks
    f16x8 kf[4][4];
    #pragma unroll
    for (int ch = 0; ch < 4; ++ch)
        #pragma unroll
        for (int ks = 0; ks < 4; ++ks)
            kf[ch][ks] = *(const f16x8*)(kb + (ib * 4 + ch) * 2048 + ks * 512 + lane * 8);

    float lsum[4] = {0.f, 0.f, 0.f, 0.f};

    for (int jc = w; jc < 64; jc += 4) {
        const _Float16* qc = qb + jc * 2048 + lane * 8;
        f16x8 q0 = *(const f16x8*)(qc);
        f16x8 q1 = *(const f16x8*)(qc + 512);
        f16x8 q2 = *(const f16x8*)(qc + 1024);
        f16x8 q3 = *(const f16x8*)(qc + 1536);
        #pragma unroll
        for (int ch = 0; ch < 4; ++ch) {
            f32x16 s = {};
            s = mfma32(q0, kf[ch][0], s);
            s = mfma32(q1, kf[ch][1], s);
            s = mfma32(q2, kf[ch][2], s);
            s = mfma32(q3, kf[ch][3], s);
            float t0 = 0.f;
            #pragma unroll
            for (int r = 0; r < 16; ++r) t0 += fexp2(s[r]);
            lsum[ch] += t0;
        }
    }

    // combine the two 16-j halves (lanes l and l+32 hold same i)
    #pragma unroll
    for (int ch = 0; ch < 4; ++ch) lsum[ch] += __shfl_xor(lsum[ch], 32);
    if (lane < 32) {
        #pragma unroll
        for (int ch = 0; ch < 4; ++ch) red[w][ch][lane] = lsum[ch];
    }
    __syncthreads();
    if (tid < 128) {
        const int ch = tid >> 5, l = tid & 31;
        float s = red[0][ch][l] + red[1][ch][l] + red[2][ch][l] + red[3][ch][l];
        float cv = -0.5f * log2f(s);
        cvals[(size_t)bh * SEQ + ib * 128 + tid] = cv;
        cshare[tid] = cv;
    }
    __syncthreads();

    // fused prescale: two 64-i halves through the 64x65 transpose tile
    const int r = tid >> 2, q = tid & 3;
    #pragma unroll
    for (int half = 0; half < 2; ++half) {
        const int i0 = ib * 128 + half * 64;
        const float cf = fexp2(cshare[half * 64 + r]);
        const _Float16* src = vT + ((size_t)bh * SEQ + i0 + r) * HD + q * 16;
        f16x8 a = *(const f16x8*)src, b2 = *(const f16x8*)(src + 8);
        #pragma unroll
        for (int k = 0; k < 8; ++k) {
            T[r][q * 16 + k]     = (float)a[k] * cf;
            T[r][q * 16 + 8 + k] = (float)b2[k] * cf;
        }
        __syncthreads();
        f16x8 o0, o1;
        #pragma unroll
        for (int k = 0; k < 8; ++k) {
            o0[k] = (_Float16)T[q * 16 + k][r];
            o1[k] = (_Float16)T[q * 16 + 8 + k][r];
        }
        const int ic  = (i0 >> 5) + (q >> 1);
        const int ksp = q & 1;
        const int dh  = r >> 5;
        _Float16* dst = vblk + (size_t)bh * (SEQ * 64)
                      + ic * 2048 + ksp * 1024 + dh * 512 + (r & 31) * 8;
        *(f16x8*)(dst)       = o0;   // hb=0
        *(f16x8*)(dst + 256) = o1;   // hb=1
        __syncthreads();             // protect T for next half
    }
}

// ---------------------------------------------------------------------------
// Pass 2 v15: v14 with launch_bounds(256,4) — live set is now 88 VGPR < the
// 128 cap this implies, so no spill (Round-17's failure was a 64 cap) and the
// scheduler targets 4 waves/SIMD instead of 2, doubling latency-hiding.
// 64-j tile, two 32-j subtiles per wave sharing K/V/c regs; 4-way i-split;
// K+V software prefetch; single-pass 32KB merge. XCD-aware bh decode.
// ---------------------------------------------------------------------------
struct KF { f16x8 k0, k1, k2, k3; };
__device__ inline KF loadKF(const _Float16* kb, int ic, int lane) {
    KF r;
    const _Float16* kc = kb + (size_t)ic * 2048 + lane * 8;
    r.k0 = *(const f16x8*)(kc);
    r.k1 = *(const f16x8*)(kc + 512);
    r.k2 = *(const f16x8*)(kc + 1024);
    r.k3 = *(const f16x8*)(kc + 1536);
    return r;
}

__global__ __launch_bounds__(256, 4)
void attn_pass2(const _Float16* __restrict__ qblk, const _Float16* __restrict__ kblk,
                const _Float16* __restrict__ vblk, const float* __restrict__ cvals,
                ushort* __restrict__ aoth, ushort* __restrict__ aotl)
{
    const int lb  = blockIdx.x;        // 1024 blocks
    const int xcd = lb & 7;
    const int idx = lb >> 3;           // 0..127
    const int bh  = xcd * 4 + (idx & 3);
    const int jt  = idx >> 2;          // 0..31 (64-j block tile)
    const int b = bh >> 3, h = bh & 7;
    const _Float16* qb = qblk + (size_t)bh * (SEQ * 64);
    const _Float16* kb = kblk + (size_t)bh * (SEQ * 64);
    const _Float16* vb = vblk + (size_t)bh * (SEQ * 64);
    const float* cp = cvals + (size_t)bh * SEQ;

    __shared__ float red[2][64][64];   // 32 KB single-pass reduce buffer

    const int tid = threadIdx.x;
    const int w = tid >> 6, lane = tid & 63, l31 = lane & 31, hb = lane >> 5;
    const int j0 = jt * 64;

    // hoist Q B-frags for both 32-j subtiles
    const _Float16* qcA = qb + (size_t)(jt * 2) * 2048 + lane * 8;
    f16x8 qf0 = *(const f16x8*)(qcA);
    f16x8 qf1 = *(const f16x8*)(qcA + 512);
    f16x8 qf2 = *(const f16x8*)(qcA + 1024);
    f16x8 qf3 = *(const f16x8*)(qcA + 1536);
    const _Float16* qcB = qcA + 2048;
    f16x8 qg0 = *(const f16x8*)(qcB);
    f16x8 qg1 = *(const f16x8*)(qcB + 512);
    f16x8 qg2 = *(const f16x8*)(qcB + 1024);
    f16x8 qg3 = *(const f16x8*)(qcB + 1536);

    f32x16 oA0 = {}, oA1 = {};   // subtile A: d [0,32) / [32,64)
    f32x16 oB0 = {}, oB1 = {};   // subtile B

    KF curK = loadKF(kb, w * 16, lane);
    KF curV = loadKF(vb, w * 16, lane);   // v00,v01,v10,v11 in k0..k3

    for (int it = 0; it < 16; ++it) {
        const int ic = w * 16 + it;
        const int i0 = ic * 32;
        // prefetch next iter's K and V (last-iter overread stays in ws, unused)
        KF nxK = loadKF(kb, ic + 1, lane);
        KF nxV = loadKF(vb, ic + 1, lane);
        // -c/2 for reg r (pre-negated; 8KB/bh -> L1-resident)
        const float* cq = cp + i0 + 4 * hb;
        float4 c0 = *(const float4*)(cq);
        float4 c1 = *(const float4*)(cq + 8);
        float4 c2 = *(const float4*)(cq + 16);
        float4 c3 = *(const float4*)(cq + 24);
        const f32x16 cinit = {c0.x, c0.y, c0.z, c0.w, c1.x, c1.y, c1.z, c1.w,
                              c2.x, c2.y, c2.z, c2.w, c3.x, c3.y, c3.z, c3.w};

        union PU { unsigned u[4]; f16x8 v; };

        // ---- subtile A ----
        {
            f32x16 s = cinit;
            s = mfma32(curK.k0, qf0, s);
            s = mfma32(curK.k1, qf1, s);
            s = mfma32(curK.k2, qf2, s);
            s = mfma32(curK.k3, qf3, s);
            unsigned pk0 = pk2u(fexp2(s[0]),  fexp2(s[1]));
            unsigned pk1 = pk2u(fexp2(s[2]),  fexp2(s[3]));
            unsigned pk2 = pk2u(fexp2(s[4]),  fexp2(s[5]));
            unsigned pk3 = pk2u(fexp2(s[6]),  fexp2(s[7]));
            unsigned pk4 = pk2u(fexp2(s[8]),  fexp2(s[9]));
            unsigned pk5 = pk2u(fexp2(s[10]), fexp2(s[11]));
            unsigned pk6 = pk2u(fexp2(s[12]), fexp2(s[13]));
            unsigned pk7 = pk2u(fexp2(s[14]), fexp2(s[15]));
            auto sA0 = __builtin_amdgcn_permlane32_swap(pk0, pk2, false, false);
            auto sB0 = __builtin_amdgcn_permlane32_swap(pk1, pk3, false, false);
            auto sA1 = __builtin_amdgcn_permlane32_swap(pk4, pk6, false, false);
            auto sB1 = __builtin_amdgcn_permlane32_swap(pk5, pk7, false, false);
            PU pa0, pa1;
            pa0.u[0] = sA0[0]; pa0.u[1] = sB0[0]; pa0.u[2] = sA0[1]; pa0.u[3] = sB0[1];
            pa1.u[0] = sA1[0]; pa1.u[1] = sB1[0]; pa1.u[2] = sA1[1]; pa1.u[3] = sB1[1];
            oA0 = mfma32(pa0.v, curV.k0, oA0);
            oA0 = mfma32(pa1.v, curV.k2, oA0);
            oA1 = mfma32(pa0.v, curV.k1, oA1);
            oA1 = mfma32(pa1.v, curV.k3, oA1);
        }
        // ---- subtile B ----
        {
            f32x16 s = cinit;
            s = mfma32(curK.k0, qg0, s);
            s = mfma32(curK.k1, qg1, s);
            s = mfma32(curK.k2, qg2, s);
            s = mfma32(curK.k3, qg3, s);
            unsigned pk0 = pk2u(fexp2(s[0]),  fexp2(s[1]));
            unsigned pk1 = pk2u(fexp2(s[2]),  fexp2(s[3]));
            unsigned pk2 = pk2u(fexp2(s[4]),  fexp2(s[5]));
            unsigned pk3 = pk2u(fexp2(s[6]),  fexp2(s[7]));
            unsigned pk4 = pk2u(fexp2(s[8]),  fexp2(s[9]));
            unsigned pk5 = pk2u(fexp2(s[10]), fexp2(s[11]));
            unsigned pk6 = pk2u(fexp2(s[12]), fexp2(s[13]));
            unsigned pk7 = pk2u(fexp2(s[14]), fexp2(s[15]));
            auto sA0 = __builtin_amdgcn_permlane32_swap(pk0, pk2, false, false);
            auto sB0 = __builtin_amdgcn_permlane32_swap(pk1, pk3, false, false);
            auto sA1 = __builtin_amdgcn_permlane32_swap(pk4, pk6, false, false);
            auto sB1 = __builtin_amdgcn_permlane32_swap(pk5, pk7, false, false);
            PU pa0, pa1;
            pa0.u[0] = sA0[0]; pa0.u[1] = sB0[0]; pa0.u[2] = sA0[1]; pa0.u[3] = sB0[1];
            pa1.u[0] = sA1[0]; pa1.u[1] = sB1[0]; pa1.u[2] = sA1[1]; pa1.u[3] = sB1[1];
            oB0 = mfma32(pa0.v, curV.k0, oB0);
            oB0 = mfma32(pa1.v, curV.k2, oB0);
            oB1 = mfma32(pa0.v, curV.k1, oB1);
            oB1 = mfma32(pa1.v, curV.k3, oB1);
        }
        curK = nxK;
        curV = nxV;
    }

    // ---- single-pass merge (both subtiles): (1->0, 3->2) then (2->0) ----
    if (w & 1) {
        #pragma unroll
        for (int r = 0; r < 16; ++r) {
            red[w >> 1][r][lane]      = oA0[r];
            red[w >> 1][r + 16][lane] = oA1[r];
            red[w >> 1][r + 32][lane] = oB0[r];
            red[w >> 1][r + 48][lane] = oB1[r];
        }
    }
    __syncthreads();
    if (!(w & 1)) {
        #pragma unroll
        for (int r = 0; r < 16; ++r) {
            oA0[r] += red[w >> 1][r][lane];
            oA1[r] += red[w >> 1][r + 16][lane];
            oB0[r] += red[w >> 1][r + 32][lane];
            oB1[r] += red[w >> 1][r + 48][lane];
        }
    }
    __syncthreads();
    if (w == 2) {
        #pragma unroll
        for (int r = 0; r < 16; ++r) {
            red[0][r][lane]      = oA0[r];
            red[0][r + 16][lane] = oA1[r];
            red[0][r + 32][lane] = oB0[r];
            red[0][r + 48][lane] = oB1[r];
        }
    }
    __syncthreads();
    if (w == 0) {
        #pragma unroll
        for (int r = 0; r < 16; ++r) {
            oA0[r] += red[0][r][lane];
            oA1[r] += red[0][r + 16][lane];
            oB0[r] += red[0][r + 32][lane];
            oB1[r] += red[0][r + 48][lane];
        }
        #pragma unroll
        for (int r = 0; r < 16; ++r) {
            const int jr = (r & 3) + 8 * (r >> 2) + 4 * hb;
            // subtile A
            {
                const int j = j0 + jr;
                const size_t row = ((size_t)b * SEQ + j) * CDIM + h * HD + l31;
                float v0 = oA0[r], v1 = oA1[r];
                ushort h0 = bf16_rne(v0), h1 = bf16_rne(v1);
                aoth[row]      = h0;
                aoth[row + 32] = h1;
                aotl[row]      = bf16_rne(v0 - bf16_to_f(h0));
                aotl[row + 32] = bf16_rne(v1 - bf16_to_f(h1));
            }
            // subtile B
            {
                const int j = j0 + 32 + jr;
                const size_t row = ((size_t)b * SEQ + j) * CDIM + h * HD + l31;
                float v0 = oB0[r], v1 = oB1[r];
                ushort h0 = bf16_rne(v0), h1 = bf16_rne(v1);
                aoth[row]      = h0;
                aoth[row + 32] = h1;
                aotl[row]      = bf16_rne(v0 - bf16_to_f(h0));
                aotl[row + 32] = bf16_rne(v1 - bf16_to_f(h1));
            }
        }
    }
}

// ---------------------------------------------------------------------------
extern "C" void kernel_launch(void* const* d_in, const int* in_sizes, int n_in,
                              void* d_out, int out_size, void* d_ws, size_t ws_size,
                              hipStream_t stream)
{
    const float* x      = (const float*)d_in[0];   // [4][512][2048]
    const float* w_qkv  = (const float*)d_in[1];   // [1536][512]
    const float* w_proj = (const float*)d_in[2];   // [512][512]
    const float* b_proj = (const float*)d_in[3];   // [512]
    float* out = (float*)d_out;                    // [4][512][2048]

    char* p = (char*)d_ws;
    auto alloc = [&](size_t bytes) { char* q = p; p += (bytes + 255) & ~(size_t)255; return q; };
    _Float16* qblk = (_Float16*)alloc((size_t)NB * NHEAD * SEQ * 64 * 2);  // 8 MB
    _Float16* kblk = (_Float16*)alloc((size_t)NB * NHEAD * SEQ * 64 * 2);  // 8 MB
    _Float16* vT   = (_Float16*)alloc((size_t)NB * NHEAD * SEQ * HD * 2);  // 8 MB
    _Float16* vblk = (_Float16*)alloc((size_t)NB * NHEAD * SEQ * 64 * 2);  // 8 MB
    float*    cvals = (float*)alloc((size_t)NB * NHEAD * SEQ * 4);         // 256 KB
    ushort*   xTh  = (ushort*)alloc((size_t)NB * SEQ * CDIM * 2);          // 8 MB
    ushort*   wqh  = (ushort*)alloc((size_t)3 * CDIM * CDIM * 2);
    ushort*   wql  = (ushort*)alloc((size_t)3 * CDIM * CDIM * 2);
    ushort*   wph  = (ushort*)alloc((size_t)CDIM * CDIM * 2);
    ushort*   wpl  = (ushort*)alloc((size_t)CDIM * CDIM * 2);
    ushort*   aoth = (ushort*)alloc((size_t)NB * SEQ * CDIM * 2);          // 8 MB
    ushort*   aotl = (ushort*)alloc((size_t)NB * SEQ * CDIM * 2);          // 8 MB

    dim3 blk(256);
    // weight conversions + input transpose (plain bf16)
    conv_w<<<dim3(512), blk, 0, stream>>>(w_qkv, w_proj, wqh, wql, wph, wpl);
    conv_x<<<dim3(SEQ / 64, CDIM / 64, NB), blk, 0, stream>>>(x, xTh);
    // qkv: q/k -> fragment-major blobs (K*SL), v -> vT rows (1-term bf16)
    gemm_sp<0><<<dim3(12, 16, NB), blk, 0, stream>>>(
        xTh, nullptr, (size_t)SEQ * CDIM, wqh, nullptr, 0,
        qblk, kblk, vT, nullptr, nullptr);
    // softmax row constants (-c/2) + fused V prescale -> V_blk
    attn_pass1<<<dim3(512), blk, 0, stream>>>(qblk, kblk, vT, cvals, vblk);
    // attention -> aoutT split bf16 (64-j blocks, XCD-local bh, K+V prefetch)
    attn_pass2<<<dim3(1024), blk, 0, stream>>>(
        qblk, kblk, vblk, cvals, aoth, aotl);
    // proj: D[co][seq] = w_proj @ aout + bias (3-term split)
    gemm_sp<1><<<dim3(16, 4, NB), blk, 0, stream>>>(
        wph, wpl, 0, aoth, aotl, (size_t)SEQ * CDIM,
        nullptr, nullptr, nullptr, out, b_proj);
}

// Round 25
// 131.451 us; speedup vs baseline: 1.1896x; 1.1896x over previous
//
#include <hip/hip_runtime.h>
#include <hip/hip_bf16.h>
#include <math.h>

#define SEQ   2048
#define NB    4
#define CDIM  512
#define NHEAD 8
#define HD    64
// scale * log2(e): folded into K channels at the qkv GEMM epilogue
#define SL    (0.125f * 1.4426950408889634f)

typedef __attribute__((ext_vector_type(8))) short short8;
typedef __attribute__((ext_vector_type(8))) _Float16 f16x8;
typedef __attribute__((ext_vector_type(4))) float f32x4;
typedef __attribute__((ext_vector_type(16))) float f32x16;

__device__ inline f32x16 mfma32(f16x8 a, f16x8 b, f32x16 c) {
    return __builtin_amdgcn_mfma_f32_32x32x16_f16(a, b, c, 0, 0, 0);
}
__device__ inline f32x4 mfmaB(short8 a, short8 b, f32x4 c) {
    return __builtin_amdgcn_mfma_f32_16x16x32_bf16(a, b, c, 0, 0, 0);
}

__device__ inline ushort bf16_rne(float f) {
    union { float f; unsigned u; } c; c.f = f;
    unsigned u = c.u + 0x7fffu + ((c.u >> 16) & 1u);
    return (ushort)(u >> 16);
}
__device__ inline float bf16_to_f(ushort h) {
    union { unsigned u; float f; } c; c.u = ((unsigned)h) << 16;
    return c.f;
}
// pack two f32 -> one VGPR of 2x f16 (RTZ)
__device__ inline unsigned pk2u(float a, float b) {
    auto p = __builtin_amdgcn_cvt_pkrtz(a, b);
    union { decltype(p) v; unsigned u; } c; c.v = p; return c.u;
}
// raw hardware 2^x via compiler builtin (hazards handled by compiler)
__device__ inline float fexp2(float x) { return __builtin_amdgcn_exp2f(x); }

// LDS tile layout (GEMM staging): [rows][64 cols of 2B] = 128B pitch, swizzled.
__device__ inline int swz_off(int row, int byte_in_row) {
    return row * 128 + (byte_in_row ^ ((((row & 7) ^ ((row >> 3) & 7))) << 4));
}
__device__ inline short8 fragB(const ushort* base, int row, int kbyte) {
    return *(const short8*)(base + (swz_off(row, kbyte) >> 1));
}

// stage 128x64 2B tile (16KB) via global_load_lds (width 16): LINEAR LDS dest,
// per-lane INVERSE-SWIZZLED global source (XOR swizzle is an involution, so
// LDS content is identical to the old reg-staged swizzled layout).
// src row pitch = 512 elems. 16 x 1KB wave-chunks; wave w owns chunks 4w..4w+3.
__device__ inline void stage128_lds(ushort* dst, const ushort* src, int tid) {
    const int w = tid >> 6, lane = tid & 63;
    #pragma unroll
    for (int i = 0; i < 4; ++i) {
        const int chunk = w * 4 + i;                 // 1KB LDS chunk index
        const int o = chunk * 1024 + lane * 16;      // this lane's dest byte
        const int row = o >> 7;
        const int byte = (o & 127) ^ ((((row & 7) ^ ((row >> 3) & 7))) << 4);
        const ushort* s = src + (size_t)row * 512 + (byte >> 1);
        __builtin_amdgcn_global_load_lds(
            (const __attribute__((address_space(1))) unsigned int*)s,
            (__attribute__((address_space(3))) unsigned int*)(dst + chunk * 512),
            16, 0, 0);
    }
}

// Fragment-major blob geometry (per bh, 2B elems):
//  Q_blk/K_blk: [chunk(64)][ks(4)][lane(64)][e(8)]  (chunk stride 2048)
//  V_blk: [ic(64)][ksp(2)][dh(2)][lane(64)][e(8)]

// ---------------------------------------------------------------------------
// conv_w: w_qkv -> bf16 hi only (qkv GEMM is 1-term); w_proj -> hi/lo split.
// ---------------------------------------------------------------------------
__global__ __launch_bounds__(256)
void conv_w(const float* __restrict__ w1, const float* __restrict__ w2,
            ushort* __restrict__ w1h, ushort* __restrict__ w1l,
            ushort* __restrict__ w2h, ushort* __restrict__ w2l)
{
    const size_t NW1 = (size_t)3 * CDIM * CDIM;
    size_t i = ((size_t)blockIdx.x * 256 + threadIdx.x) * 8;
    const bool isW1 = (i < NW1);
    const float* src; ushort *dh, *dl;
    if (isW1) { src = w1 + i; dh = w1h + i; dl = w1l + i; }
    else { size_t j = i - NW1; src = w2 + j; dh = w2h + j; dl = w2l + j; }
    float4 a = *(const float4*)src, b = *(const float4*)(src + 4);
    float f[8] = {a.x, a.y, a.z, a.w, b.x, b.y, b.z, b.w};
    short8 hv, lv;
    #pragma unroll
    for (int e = 0; e < 8; ++e) {
        ushort hi = bf16_rne(f[e]);
        hv[e] = (short)hi;
        lv[e] = (short)bf16_rne(f[e] - bf16_to_f(hi));
    }
    *(short8*)dh = hv;
    if (!isW1) *(short8*)dl = lv;   // lo half only needed for w_proj
}

// ---------------------------------------------------------------------------
// conv_x: x[b][c][n] f32 -> xT[b][n][c] plain bf16 (LDS-tiled transpose)
// ---------------------------------------------------------------------------
__global__ __launch_bounds__(256)
void conv_x(const float* __restrict__ x, ushort* __restrict__ xh)
{
    __shared__ float T[64][65];
    const int n0 = blockIdx.x * 64, c0 = blockIdx.y * 64, b = blockIdx.z;
    const int t = threadIdx.x, r = t >> 2, q = t & 3;
    const float* src = x + ((size_t)b * CDIM + c0 + r) * SEQ + n0 + q * 16;
    #pragma unroll
    for (int c = 0; c < 4; ++c) {
        float4 v = *(const float4*)(src + c * 4);
        T[r][q * 16 + c * 4 + 0] = v.x; T[r][q * 16 + c * 4 + 1] = v.y;
        T[r][q * 16 + c * 4 + 2] = v.z; T[r][q * 16 + c * 4 + 3] = v.w;
    }
    __syncthreads();
    short8 hv[2];
    #pragma unroll
    for (int k = 0; k < 16; ++k)
        hv[k >> 3][k & 7] = (short)bf16_rne(T[q * 16 + k][r]);
    size_t o = ((size_t)b * SEQ + n0 + r) * CDIM + c0 + q * 16;
    *(short8*)(xh + o) = hv[0]; *(short8*)(xh + o + 8) = hv[1];
}

// ---------------------------------------------------------------------------
// Split-bf16 MFMA GEMM: D[m][n] = sum_k A[m][k]*B[n][k], K=512.
// Block 128m x 128n, BK=64, 4 waves (2x2), 64x64 per wave.
// Staging via global_load_lds (linear dest + pre-swizzled source).
// MODE 0 (qkv): A = xT plain bf16, B = wh plain bf16 (1 MFMA term); m=seq,
//    n=ch -> q/k into fragment-major Q_blk/K_blk fp16 (K scaled SL), v -> vT.
// MODE 1 (proj): A = w split, B = aot split (3 terms); m=co, n=seq -> out+bias
// ---------------------------------------------------------------------------
template<int MODE>
__global__ __launch_bounds__(256)
void gemm_sp(const ushort* __restrict__ A0, const ushort* __restrict__ A1, size_t sA,
             const ushort* __restrict__ B0, const ushort* __restrict__ B1, size_t sB,
             _Float16* __restrict__ qblk, _Float16* __restrict__ kblk,
             _Float16* __restrict__ vT,
             float* __restrict__ outp, const float* __restrict__ bias)
{
    const int bn = blockIdx.x * 128, bm = blockIdx.y * 128, bat = blockIdx.z;
    __shared__ __align__(16) ushort sA0[8192], sA1[8192], sB0[8192], sB1[8192];
    const int tid = threadIdx.x;
    const int w = tid >> 6, lane = tid & 63, l15 = lane & 15, g = lane >> 4;
    const int wm = w >> 1, wn = w & 1;
    const ushort* Ah = A0 + sA * bat + (size_t)bm * 512;
    const ushort* Al = (MODE == 1) ? A1 + sA * bat + (size_t)bm * 512 : nullptr;
    const ushort* Bh = B0 + sB * bat + (size_t)bn * 512;
    const ushort* Bl = (MODE == 1) ? B1 + sB * bat + (size_t)bn * 512 : nullptr;

    f32x4 acc[4][4] = {};

    for (int k0 = 0; k0 < 512; k0 += 64) {
        __syncthreads();
        stage128_lds(sA0, Ah + k0, tid);
        stage128_lds(sB0, Bh + k0, tid);
        if (MODE == 1) {
            stage128_lds(sA1, Al + k0, tid);
            stage128_lds(sB1, Bl + k0, tid);
        }
        __syncthreads();
        #pragma unroll
        for (int kh = 0; kh < 2; ++kh) {
            short8 bh[4], bl[4];
            #pragma unroll
            for (int nf = 0; nf < 4; ++nf) {
                bh[nf] = fragB(sB0, 64 * wn + 16 * nf + l15, kh * 64 + g * 16);
                if (MODE == 1)
                    bl[nf] = fragB(sB1, 64 * wn + 16 * nf + l15, kh * 64 + g * 16);
            }
            #pragma unroll
            for (int mf = 0; mf < 4; ++mf) {
                short8 ah = fragB(sA0, 64 * wm + 16 * mf + l15, kh * 64 + g * 16);
                #pragma unroll
                for (int nf = 0; nf < 4; ++nf) {
                    acc[mf][nf] = mfmaB(ah, bh[nf], acc[mf][nf]);
                    if (MODE == 1)
                        acc[mf][nf] = mfmaB(ah, bl[nf], acc[mf][nf]);
                }
                if (MODE == 1) {
                    short8 al = fragB(sA1, 64 * wm + 16 * mf + l15, kh * 64 + g * 16);
                    #pragma unroll
                    for (int nf = 0; nf < 4; ++nf)
                        acc[mf][nf] = mfmaB(al, bh[nf], acc[mf][nf]);
                }
            }
        }
    }

    if (MODE == 0) {
        #pragma unroll
        for (int nf = 0; nf < 4; ++nf) {
            const int c0 = bn + 64 * wn + 16 * nf;   // frag-uniform (16 | boundaries)
            const int h = c0 / 192, rr = c0 % 192;
            if (rr < 128) {
                // q (rr<64) or k (64..127): fragment-major blob, K scaled by SL
                const float sc = (rr < 64) ? 1.0f : SL;
                const int dpr = (rr & 63) + l15;            // d' in [0,64)
                _Float16* blob = (rr < 64) ? qblk : kblk;
                _Float16* base = blob + (size_t)(bat * NHEAD + h) * (SEQ * 64)
                               + (dpr >> 4) * 512 + (((dpr >> 3) & 1) * 32) * 8
                               + (dpr & 7);
                #pragma unroll
                for (int mf = 0; mf < 4; ++mf)
                    #pragma unroll
                    for (int r = 0; r < 4; ++r) {
                        const int sj = bm + 64 * wm + 16 * mf + 4 * g + r;
                        base[(sj >> 5) * 2048 + (sj & 31) * 8] =
                            (_Float16)(acc[mf][nf][r] * sc);
                    }
            } else {
                _Float16* base = vT + ((size_t)(bat * NHEAD + h) * SEQ) * HD + (rr - 128) + l15;
                #pragma unroll
                for (int mf = 0; mf < 4; ++mf)
                    #pragma unroll
                    for (int r = 0; r < 4; ++r) {
                        const int sj = bm + 64 * wm + 16 * mf + 4 * g + r;
                        base[(size_t)sj * HD] = (_Float16)acc[mf][nf][r];
                    }
            }
        }
    } else {
        #pragma unroll
        for (int mf = 0; mf < 4; ++mf)
            #pragma unroll
            for (int r = 0; r < 4; ++r) {
                const int co = bm + 64 * wm + 16 * mf + 4 * g + r;
                const float bv = bias[co];
                float* base = outp + ((size_t)bat * CDIM + co) * SEQ + bn + 64 * wn + l15;
                #pragma unroll
                for (int nf = 0; nf < 4; ++nf)
                    base[16 * nf] = acc[mf][nf][r] + bv;
            }
    }
}

// ---------------------------------------------------------------------------
// Pass 1 v9 (128-i blocks, fused V prescale): cvals_i = -0.5*log2 sum_j 2^S,
// then scale/transpose this block's 128 V rows into V_blk using the fresh c.
// XCD-aware bh decode. K-frags (4 chunks) hoisted; j-reduction lane-local.
// ---------------------------------------------------------------------------
__global__ __launch_bounds__(256, 3)
void attn_pass1(const _Float16* __restrict__ qblk, const _Float16* __restrict__ kblk,
                const _Float16* __restrict__ vT, float* __restrict__ cvals,
                _Float16* __restrict__ vblk)
{
    const int lb = blockIdx.x;         // 512 blocks
    const int xcd = lb & 7, idx = lb >> 3;
    const int bh = xcd * 4 + (idx & 3);
    const int ib = idx >> 2;           // 0..15 (128-i tile)
    const _Float16* qb = qblk + (size_t)bh * (SEQ * 64);
    const _Float16* kb = kblk + (size_t)bh * (SEQ * 64);
    const int tid = threadIdx.x, w = tid >> 6, lane = tid & 63;

    __shared__ float red[4][4][32];
    __shared__ float cshare[128];
    __shared__ float T[64][65];

    // hoist K B-frags for the block's four i-chunks
    f16x8 kf[4][4];
    #pragma unroll
    for (int ch = 0; ch < 4; ++ch)
        #pragma unroll
        for (int ks = 0; ks < 4; ++ks)
            kf[ch][ks] = *(const f16x8*)(kb + (ib * 4 + ch) * 2048 + ks * 512 + lane * 8);

    float lsum[4] = {0.f, 0.f, 0.f, 0.f};

    for (int jc = w; jc < 64; jc += 4) {
        const _Float16* qc = qb + jc * 2048 + lane * 8;
        f16x8 q0 = *(const f16x8*)(qc);
        f16x8 q1 = *(const f16x8*)(qc + 512);
        f16x8 q2 = *(const f16x8*)(qc + 1024);
        f16x8 q3 = *(const f16x8*)(qc + 1536);
        #pragma unroll
        for (int ch = 0; ch < 4; ++ch) {
            f32x16 s = {};
            s = mfma32(q0, kf[ch][0], s);
            s = mfma32(q1, kf[ch][1], s);
            s = mfma32(q2, kf[ch][2], s);
            s = mfma32(q3, kf[ch][3], s);
            float t0 = 0.f;
            #pragma unroll
            for (int r = 0; r < 16; ++r) t0 += fexp2(s[r]);
            lsum[ch] += t0;
        }
    }

    // combine the two 16-j halves (lanes l and l+32 hold same i)
    #pragma unroll
    for (int ch = 0; ch < 4; ++ch) lsum[ch] += __shfl_xor(lsum[ch], 32);
    if (lane < 32) {
        #pragma unroll
        for (int ch = 0; ch < 4; ++ch) red[w][ch][lane] = lsum[ch];
    }
    __syncthreads();
    if (tid < 128) {
        const int ch = tid >> 5, l = tid & 31;
        float s = red[0][ch][l] + red[1][ch][l] + red[2][ch][l] + red[3][ch][l];
        float cv = -0.5f * log2f(s);
        cvals[(size_t)bh * SEQ + ib * 128 + tid] = cv;
        cshare[tid] = cv;
    }
    __syncthreads();

    // fused prescale: two 64-i halves through the 64x65 transpose tile
    const int r = tid >> 2, q = tid & 3;
    #pragma unroll
    for (int half = 0; half < 2; ++half) {
        const int i0 = ib * 128 + half * 64;
        const float cf = fexp2(cshare[half * 64 + r]);
        const _Float16* src = vT + ((size_t)bh * SEQ + i0 + r) * HD + q * 16;
        f16x8 a = *(const f16x8*)src, b2 = *(const f16x8*)(src + 8);
        #pragma unroll
        for (int k = 0; k < 8; ++k) {
            T[r][q * 16 + k]     = (float)a[k] * cf;
            T[r][q * 16 + 8 + k] = (float)b2[k] * cf;
        }
        __syncthreads();
        f16x8 o0, o1;
        #pragma unroll
        for (int k = 0; k < 8; ++k) {
            o0[k] = (_Float16)T[q * 16 + k][r];
            o1[k] = (_Float16)T[q * 16 + 8 + k][r];
        }
        const int ic  = (i0 >> 5) + (q >> 1);
        const int ksp = q & 1;
        const int dh  = r >> 5;
        _Float16* dst = vblk + (size_t)bh * (SEQ * 64)
                      + ic * 2048 + ksp * 1024 + dh * 512 + (r & 31) * 8;
        *(f16x8*)(dst)       = o0;   // hb=0
        *(f16x8*)(dst + 256) = o1;   // hb=1
        __syncthreads();             // protect T for next half
    }
}

// ---------------------------------------------------------------------------
// Pass 2 v14 (measured best, Round 20-23): launch_bounds(256,2), 88 VGPR,
// no spill. 64-j tile, two 32-j subtiles per wave sharing K/V/c regs;
// 4-way i-split; K+V software prefetch; single-pass 32KB merge.
// XCD-aware bh decode. In-register S->P transpose; HW exp2.
// ---------------------------------------------------------------------------
struct KF { f16x8 k0, k1, k2, k3; };
__device__ inline KF loadKF(const _Float16* kb, int ic, int lane) {
    KF r;
    const _Float16* kc = kb + (size_t)ic * 2048 + lane * 8;
    r.k0 = *(const f16x8*)(kc);
    r.k1 = *(const f16x8*)(kc + 512);
    r.k2 = *(const f16x8*)(kc + 1024);
    r.k3 = *(const f16x8*)(kc + 1536);
    return r;
}

__global__ __launch_bounds__(256, 2)
void attn_pass2(const _Float16* __restrict__ qblk, const _Float16* __restrict__ kblk,
                const _Float16* __restrict__ vblk, const float* __restrict__ cvals,
                ushort* __restrict__ aoth, ushort* __restrict__ aotl)
{
    const int lb  = blockIdx.x;        // 1024 blocks
    const int xcd = lb & 7;
    const int idx = lb >> 3;           // 0..127
    const int bh  = xcd * 4 + (idx & 3);
    const int jt  = idx >> 2;          // 0..31 (64-j block tile)
    const int b = bh >> 3, h = bh & 7;
    const _Float16* qb = qblk + (size_t)bh * (SEQ * 64);
    const _Float16* kb = kblk + (size_t)bh * (SEQ * 64);
    const _Float16* vb = vblk + (size_t)bh * (SEQ * 64);
    const float* cp = cvals + (size_t)bh * SEQ;

    __shared__ float red[2][64][64];   // 32 KB single-pass reduce buffer

    const int tid = threadIdx.x;
    const int w = tid >> 6, lane = tid & 63, l31 = lane & 31, hb = lane >> 5;
    const int j0 = jt * 64;

    // hoist Q B-frags for both 32-j subtiles
    const _Float16* qcA = qb + (size_t)(jt * 2) * 2048 + lane * 8;
    f16x8 qf0 = *(const f16x8*)(qcA);
    f16x8 qf1 = *(const f16x8*)(qcA + 512);
    f16x8 qf2 = *(const f16x8*)(qcA + 1024);
    f16x8 qf3 = *(const f16x8*)(qcA + 1536);
    const _Float16* qcB = qcA + 2048;
    f16x8 qg0 = *(const f16x8*)(qcB);
    f16x8 qg1 = *(const f16x8*)(qcB + 512);
    f16x8 qg2 = *(const f16x8*)(qcB + 1024);
    f16x8 qg3 = *(const f16x8*)(qcB + 1536);

    f32x16 oA0 = {}, oA1 = {};   // subtile A: d [0,32) / [32,64)
    f32x16 oB0 = {}, oB1 = {};   // subtile B

    KF curK = loadKF(kb, w * 16, lane);
    KF curV = loadKF(vb, w * 16, lane);   // v00,v01,v10,v11 in k0..k3

    for (int it = 0; it < 16; ++it) {
        const int ic = w * 16 + it;
        const int i0 = ic * 32;
        // prefetch next iter's K and V (last-iter overread stays in ws, unused)
        KF nxK = loadKF(kb, ic + 1, lane);
        KF nxV = loadKF(vb, ic + 1, lane);
        // -c/2 for reg r (pre-negated; 8KB/bh -> L1-resident)
        const float* cq = cp + i0 + 4 * hb;
        float4 c0 = *(const float4*)(cq);
        float4 c1 = *(const float4*)(cq + 8);
        float4 c2 = *(const float4*)(cq + 16);
        float4 c3 = *(const float4*)(cq + 24);
        const f32x16 cinit = {c0.x, c0.y, c0.z, c0.w, c1.x, c1.y, c1.z, c1.w,
                              c2.x, c2.y, c2.z, c2.w, c3.x, c3.y, c3.z, c3.w};

        union PU { unsigned u[4]; f16x8 v; };

        // ---- subtile A ----
        {
            f32x16 s = cinit;
            s = mfma32(curK.k0, qf0, s);
            s = mfma32(curK.k1, qf1, s);
            s = mfma32(curK.k2, qf2, s);
            s = mfma32(curK.k3, qf3, s);
            unsigned pk0 = pk2u(fexp2(s[0]),  fexp2(s[1]));
            unsigned pk1 = pk2u(fexp2(s[2]),  fexp2(s[3]));
            unsigned pk2 = pk2u(fexp2(s[4]),  fexp2(s[5]));
            unsigned pk3 = pk2u(fexp2(s[6]),  fexp2(s[7]));
            unsigned pk4 = pk2u(fexp2(s[8]),  fexp2(s[9]));
            unsigned pk5 = pk2u(fexp2(s[10]), fexp2(s[11]));
            unsigned pk6 = pk2u(fexp2(s[12]), fexp2(s[13]));
            unsigned pk7 = pk2u(fexp2(s[14]), fexp2(s[15]));
            auto sA0 = __builtin_amdgcn_permlane32_swap(pk0, pk2, false, false);
            auto sB0 = __builtin_amdgcn_permlane32_swap(pk1, pk3, false, false);
            auto sA1 = __builtin_amdgcn_permlane32_swap(pk4, pk6, false, false);
            auto sB1 = __builtin_amdgcn_permlane32_swap(pk5, pk7, false, false);
            PU pa0, pa1;
            pa0.u[0] = sA0[0]; pa0.u[1] = sB0[0]; pa0.u[2] = sA0[1]; pa0.u[3] = sB0[1];
            pa1.u[0] = sA1[0]; pa1.u[1] = sB1[0]; pa1.u[2] = sA1[1]; pa1.u[3] = sB1[1];
            oA0 = mfma32(pa0.v, curV.k0, oA0);
            oA0 = mfma32(pa1.v, curV.k2, oA0);
            oA1 = mfma32(pa0.v, curV.k1, oA1);
            oA1 = mfma32(pa1.v, curV.k3, oA1);
        }
        // ---- subtile B ----
        {
            f32x16 s = cinit;
            s = mfma32(curK.k0, qg0, s);
            s = mfma32(curK.k1, qg1, s);
            s = mfma32(curK.k2, qg2, s);
            s = mfma32(curK.k3, qg3, s);
            unsigned pk0 = pk2u(fexp2(s[0]),  fexp2(s[1]));
            unsigned pk1 = pk2u(fexp2(s[2]),  fexp2(s[3]));
            unsigned pk2 = pk2u(fexp2(s[4]),  fexp2(s[5]));
            unsigned pk3 = pk2u(fexp2(s[6]),  fexp2(s[7]));
            unsigned pk4 = pk2u(fexp2(s[8]),  fexp2(s[9]));
            unsigned pk5 = pk2u(fexp2(s[10]), fexp2(s[11]));
            unsigned pk6 = pk2u(fexp2(s[12]), fexp2(s[13]));
            unsigned pk7 = pk2u(fexp2(s[14]), fexp2(s[15]));
            auto sA0 = __builtin_amdgcn_permlane32_swap(pk0, pk2, false, false);
            auto sB0 = __builtin_amdgcn_permlane32_swap(pk1, pk3, false, false);
            auto sA1 = __builtin_amdgcn_permlane32_swap(pk4, pk6, false, false);
            auto sB1 = __builtin_amdgcn_permlane32_swap(pk5, pk7, false, false);
            PU pa0, pa1;
            pa0.u[0] = sA0[0]; pa0.u[1] = sB0[0]; pa0.u[2] = sA0[1]; pa0.u[3] = sB0[1];
            pa1.u[0] = sA1[0]; pa1.u[1] = sB1[0]; pa1.u[2] = sA1[1]; pa1.u[3] = sB1[1];
            oB0 = mfma32(pa0.v, curV.k0, oB0);
            oB0 = mfma32(pa1.v, curV.k2, oB0);
            oB1 = mfma32(pa0.v, curV.k1, oB1);
            oB1 = mfma32(pa1.v, curV.k3, oB1);
        }
        curK = nxK;
        curV = nxV;
    }

    // ---- single-pass merge (both subtiles): (1->0, 3->2) then (2->0) ----
    if (w & 1) {
        #pragma unroll
        for (int r = 0; r < 16; ++r) {
            red[w >> 1][r][lane]      = oA0[r];
            red[w >> 1][r + 16][lane] = oA1[r];
            red[w >> 1][r + 32][lane] = oB0[r];
            red[w >> 1][r + 48][lane] = oB1[r];
        }
    }
    __syncthreads();
    if (!(w & 1)) {
        #pragma unroll
        for (int r = 0; r < 16; ++r) {
            oA0[r] += red[w >> 1][r][lane];
            oA1[r] += red[w >> 1][r + 16][lane];
            oB0[r] += red[w >> 1][r + 32][lane];
            oB1[r] += red[w >> 1][r + 48][lane];
        }
    }
    __syncthreads();
    if (w == 2) {
        #pragma unroll
        for (int r = 0; r < 16; ++r) {
            red[0][r][lane]      = oA0[r];
            red[0][r + 16][lane] = oA1[r];
            red[0][r + 32][lane] = oB0[r];
            red[0][r + 48][lane] = oB1[r];
        }
    }
    __syncthreads();
    if (w == 0) {
        #pragma unroll
        for (int r = 0; r < 16; ++r) {
            oA0[r] += red[0][r][lane];
            oA1[r] += red[0][r + 16][lane];
            oB0[r] += red[0][r + 32][lane];
            oB1[r] += red[0][r + 48][lane];
        }
        #pragma unroll
        for (int r = 0; r < 16; ++r) {
            const int jr = (r & 3) + 8 * (r >> 2) + 4 * hb;
            // subtile A
            {
                const int j = j0 + jr;
                const size_t row = ((size_t)b * SEQ + j) * CDIM + h * HD + l31;
                float v0 = oA0[r], v1 = oA1[r];
                ushort h0 = bf16_rne(v0), h1 = bf16_rne(v1);
                aoth[row]      = h0;
                aoth[row + 32] = h1;
                aotl[row]      = bf16_rne(v0 - bf16_to_f(h0));
                aotl[row + 32] = bf16_rne(v1 - bf16_to_f(h1));
            }
            // subtile B
            {
                const int j = j0 + 32 + jr;
                const size_t row = ((size_t)b * SEQ + j) * CDIM + h * HD + l31;
                float v0 = oB0[r], v1 = oB1[r];
                ushort h0 = bf16_rne(v0), h1 = bf16_rne(v1);
                aoth[row]      = h0;
                aoth[row + 32] = h1;
                aotl[row]      = bf16_rne(v0 - bf16_to_f(h0));
                aotl[row + 32] = bf16_rne(v1 - bf16_to_f(h1));
            }
        }
    }
}

// ---------------------------------------------------------------------------
extern "C" void kernel_launch(void* const* d_in, const int* in_sizes, int n_in,
                              void* d_out, int out_size, void* d_ws, size_t ws_size,
                              hipStream_t stream)
{
    const float* x      = (const float*)d_in[0];   // [4][512][2048]
    const float* w_qkv  = (const float*)d_in[1];   // [1536][512]
    const float* w_proj = (const float*)d_in[2];   // [512][512]
    const float* b_proj = (const float*)d_in[3];   // [512]
    float* out = (float*)d_out;                    // [4][512][2048]

    char* p = (char*)d_ws;
    auto alloc = [&](size_t bytes) { char* q = p; p += (bytes + 255) & ~(size_t)255; return q; };
    _Float16* qblk = (_Float16*)alloc((size_t)NB * NHEAD * SEQ * 64 * 2);  // 8 MB
    _Float16* kblk = (_Float16*)alloc((size_t)NB * NHEAD * SEQ * 64 * 2);  // 8 MB
    _Float16* vT   = (_Float16*)alloc((size_t)NB * NHEAD * SEQ * HD * 2);  // 8 MB
    _Float16* vblk = (_Float16*)alloc((size_t)NB * NHEAD * SEQ * 64 * 2);  // 8 MB
    float*    cvals = (float*)alloc((size_t)NB * NHEAD * SEQ * 4);         // 256 KB
    ushort*   xTh  = (ushort*)alloc((size_t)NB * SEQ * CDIM * 2);          // 8 MB
    ushort*   wqh  = (ushort*)alloc((size_t)3 * CDIM * CDIM * 2);
    ushort*   wql  = (ushort*)alloc((size_t)3 * CDIM * CDIM * 2);
    ushort*   wph  = (ushort*)alloc((size_t)CDIM * CDIM * 2);
    ushort*   wpl  = (ushort*)alloc((size_t)CDIM * CDIM * 2);
    ushort*   aoth = (ushort*)alloc((size_t)NB * SEQ * CDIM * 2);          // 8 MB
    ushort*   aotl = (ushort*)alloc((size_t)NB * SEQ * CDIM * 2);          // 8 MB

    dim3 blk(256);
    // weight conversions + input transpose (plain bf16)
    conv_w<<<dim3(512), blk, 0, stream>>>(w_qkv, w_proj, wqh, wql, wph, wpl);
    conv_x<<<dim3(SEQ / 64, CDIM / 64, NB), blk, 0, stream>>>(x, xTh);
    // qkv: q/k -> fragment-major blobs (K*SL), v -> vT rows (1-term bf16)
    gemm_sp<0><<<dim3(12, 16, NB), blk, 0, stream>>>(
        xTh, nullptr, (size_t)SEQ * CDIM, wqh, nullptr, 0,
        qblk, kblk, vT, nullptr, nullptr);
    // softmax row constants (-c/2) + fused V prescale -> V_blk
    attn_pass1<<<dim3(512), blk, 0, stream>>>(qblk, kblk, vT, cvals, vblk);
    // attention -> aoutT split bf16 (64-j blocks, XCD-local bh, K+V prefetch)
    attn_pass2<<<dim3(1024), blk, 0, stream>>>(
        qblk, kblk, vblk, cvals, aoth, aotl);
    // proj: D[co][seq] = w_proj @ aout + bias (3-term split)
    gemm_sp<1><<<dim3(16, 4, NB), blk, 0, stream>>>(
        wph, wpl, 0, aoth, aotl, (size_t)SEQ * CDIM,
        nullptr, nullptr, nullptr, out, b_proj);
}